// Round 10
// baseline (254.313 us; speedup 1.0000x reference)
//
#include <hip/hip_runtime.h>
#include <math.h>

constexpr int kH = 64, kW = 128, kB = 2, kS = 4;
constexpr int kNP = kH * kW;          // 8192 points per set
constexpr int kPairs = kB * kS;       // 8
constexpr int kDirs = kPairs * 2;     // 16
constexpr float kPen = 32768.0f;      // exclusion penalty (bf16-exact pow2)
constexpr float kPi = 3.14159265358979323846f;
constexpr float kFovUp = 3.0f * kPi / 180.0f;
constexpr float kFovDown = -25.0f * kPi / 180.0f;

typedef short short8 __attribute__((ext_vector_type(8)));
typedef unsigned short ushort8 __attribute__((ext_vector_type(8)));
typedef float floatx4 __attribute__((ext_vector_type(4)));

// nn tiling (mfma_f32_16x16x32_bf16, layouts HW-verified + R7-passed):
// block = 256 (4 waves); per wave 8 query tiles of 16 = 128 queries
// -> 512 queries/block. Candidate chunk = 1024 staged in LDS (32 KB).
constexpr int NCC = 8;                // candidate chunks
constexpr int CCH = kNP / NCC;        // 1024 candidates
constexpr int NQB = 16;               // query blocks (8192/512)
// grid = 16 * 16 * 8 = 2048 blocks, 128 blocks per dir

// ws layout (float offsets)
// cf   : [kDirs][kNP][16] bf16 -> 1048576 floats @ 0    (4 MB)
//        grouped per 16 candidates: [16 x lo8][16 x hi8] (256 shorts/tile)
// pts  : [kDirs][kNP] float4   -> 524288 @ 1048576      (2 MB)
// min  : [kDirs][kNP] u32      -> 131072 @ 1572864      (0.5 MB)
// mval : [kDirs] f32           -> 16  @ 1703936
// dcnt : [kDirs] u32           -> 16  @ 1703952
// acnt : u32                   -> 1   @ 1703968
constexpr size_t OFF_PTS = 1048576;
constexpr size_t OFF_MIN = 1572864;
constexpr size_t OFF_MVAL = 1703936;
constexpr size_t OFF_DCNT = 1703952;
constexpr size_t OFF_ACNT = 1703968;

__device__ __forceinline__ unsigned short f2bf(float v) {
  unsigned u = __float_as_uint(v);
  unsigned r = u + 0x7FFFu + ((u >> 16) & 1u);   // RNE
  return (unsigned short)(r >> 16);
}
__device__ __forceinline__ float bf2f(unsigned short b) {
  return __uint_as_float(((unsigned)b) << 16);
}

// MFMA with FORCED VGPR destination. The compiler otherwise routes C/D
// through AGPRs and pays 8 v_accvgpr moves per MFMA (R7), serializes (R8),
// or spills (R9). Hazard handling: MFMA-write -> VALU-read wait states are
// baked in as 2x s_nop 7 (16 cyc > worst-case ~11 for a 4-pass MFMA), so
// ordinary fminf consumers are safe. (R3/R4/R6 corruption was the OTHER
// direction: intrinsic-MFMA result read by INLINEASM, which the hazard
// recognizer does not protect.)
__device__ __forceinline__ floatx4 mfma_bf16_v(short8 a, short8 b, floatx4 c) {
  floatx4 d;
  asm("v_mfma_f32_16x16x32_bf16 %0, %1, %2, %3\n\t"
      "s_nop 7\n\t"
      "s_nop 7"
      : "=&v"(d) : "v"(a), "v"(b), "v"(c));
  return d;
}

// Candidate record F (16 bf16 slots; K-quads: q0=k0..7, q1=k8..15, q2/q3=0)
// pairs with query record G:
//  k : 0    1    2    3    4    5    6    7  | 8    9    10   11   12-15
//  F : Xh   Xl   Xh   Yh   Yl   Yh   Zh   Zl | Zh   Ch   Cl   Cl2  0
//  G : xh   xh   xl   yh   yh   yl   zh   zh | zl   1    1    1    0
// sum_k F*G = X*x + Y*y + Z*z + ct  (drops only lo*lo terms ~2e-4)
__global__ __launch_bounds__(256) void prep_kernel(
    const float* __restrict__ rv, const float* __restrict__ tgt,
    unsigned short* __restrict__ cf, float4* __restrict__ pts,
    unsigned* __restrict__ minarr, float* __restrict__ mval,
    unsigned* __restrict__ dcnt, unsigned* __restrict__ acnt) {
  int idx = blockIdx.x * 256 + threadIdx.x;   // [0, kPairs*kNP)
  int p = idx >> 13;
  int k = idx & (kNP - 1);
  int h = k >> 7;
  int w = k & 127;

  float r = rv[idx];
  float pitch = (1.0f - (h + 0.5f) * (1.0f / kH)) * (kFovUp - kFovDown) + kFovDown;
  float yaw = -(((w + 0.5f) * (1.0f / kW)) * 2.0f - 1.0f) * kPi;
  float cp = __cosf(pitch), sp = __sinf(pitch);
  float cy = __cosf(yaw), sy = __sinf(yaw);
  float px = r * cp * cy, py = r * cp * sy, pz = r * sp;
  float mo = (r > 0.0f) ? 1.0f : 0.0f;

  const float* tb = tgt + (size_t)p * 4 * kNP;
  float mt = (tb[k] > 0.0f) ? 1.0f : 0.0f;
  float tx = tb[kNP + k], ty = tb[2 * kNP + k], tz = tb[3 * kNP + k];

  float no = px * px + py * py + pz * pz;
  float nt = tx * tx + ty * ty + tz * tz;
  float co = no + kPen * (1.0f - mo);
  float ct = nt + kPen * (1.0f - mt);

  int d0 = 2 * p, d1 = d0 + 1;
  // pts.w < 16384 <=> valid query, and equals |p|^2 then.
  pts[(size_t)d0 * kNP + k] = make_float4(px, py, pz, co);
  pts[(size_t)d1 * kNP + k] = make_float4(tx, ty, tz, ct);

  // candidate records, tile-grouped: [16 x lo8][16 x hi8] per 16 candidates
  {
    float X = -2.0f * tx, Y = -2.0f * ty, Z = -2.0f * tz;
    unsigned short Xh = f2bf(X), Yh = f2bf(Y), Zh = f2bf(Z);
    unsigned short Xl = f2bf(X - bf2f(Xh));
    unsigned short Yl = f2bf(Y - bf2f(Yh));
    unsigned short Zl = f2bf(Z - bf2f(Zh));
    unsigned short Ch = f2bf(ct);
    float c1 = ct - bf2f(Ch);
    unsigned short Cl = f2bf(c1);
    unsigned short Cl2 = f2bf(c1 - bf2f(Cl));
    size_t base = (size_t)d0 * kNP * 16 + (size_t)(k >> 4) * 256 + (size_t)(k & 15) * 8;
    *(ushort8*)(cf + base) = (ushort8){Xh, Xl, Xh, Yh, Yl, Yh, Zh, Zl};
    *(ushort8*)(cf + base + 128) = (ushort8){Zh, Ch, Cl, Cl2, 0, 0, 0, 0};
  }
  {
    float X = -2.0f * px, Y = -2.0f * py, Z = -2.0f * pz;
    unsigned short Xh = f2bf(X), Yh = f2bf(Y), Zh = f2bf(Z);
    unsigned short Xl = f2bf(X - bf2f(Xh));
    unsigned short Yl = f2bf(Y - bf2f(Yh));
    unsigned short Zl = f2bf(Z - bf2f(Zh));
    unsigned short Ch = f2bf(co);
    float c1 = co - bf2f(Ch);
    unsigned short Cl = f2bf(c1);
    unsigned short Cl2 = f2bf(c1 - bf2f(Cl));
    size_t base = (size_t)d1 * kNP * 16 + (size_t)(k >> 4) * 256 + (size_t)(k & 15) * 8;
    *(ushort8*)(cf + base) = (ushort8){Xh, Xl, Xh, Yh, Yl, Yh, Zh, Zl};
    *(ushort8*)(cf + base + 128) = (ushort8){Zh, Ch, Cl, Cl2, 0, 0, 0, 0};
  }

  minarr[(size_t)d0 * kNP + k] = 0xFFFFFFFFu;
  minarr[(size_t)d1 * kNP + k] = 0xFFFFFFFFu;
  if (idx < kDirs) { dcnt[idx] = 0u; mval[idx] = 0.0f; }
  if (idx == kDirs) *acnt = 0u;
}

__global__ __launch_bounds__(256, 4) void nn_kernel(
    const unsigned short* __restrict__ cf, const float4* __restrict__ pts,
    unsigned* __restrict__ minarr, float* __restrict__ mval,
    unsigned* __restrict__ dcnt, unsigned* __restrict__ acnt,
    float* __restrict__ out) {
  __shared__ __align__(16) unsigned short sc[CCH * 16 + 16];  // 32KB + zero blk
  __shared__ unsigned s_ticket;
  __shared__ float sw[4], sm[4];

  int bid = blockIdx.x;
  int d = bid >> 7;            // 128 blocks per dir
  int qb = (bid >> 3) & 15;
  int ch = bid & 7;
  int t = threadIdx.x;

  // stage chunk (32 KB) + zero block for quads 2-3
  const float4* src = (const float4*)(cf + (size_t)d * kNP * 16 + (size_t)ch * 16384);
  float4* dst = (float4*)sc;
#pragma unroll
  for (int i = 0; i < 8; ++i) dst[t + i * 256] = src[t + i * 256];
  if (t < 2) ((float4*)(sc + CCH * 16))[t] = make_float4(0.f, 0.f, 0.f, 0.f);
  __syncthreads();

  int wave = t >> 6, lane = t & 63;
  int n = lane & 15, q = lane >> 4;    // q = K-quad (HW-verified layout)
  int qbase = d * kNP + qb * 512 + wave * 128;

  const short one_bf = (short)0x3F80;  // bf16(1.0)
  short8 bfr[8];
  float mn[8];
#pragma unroll
  for (int i = 0; i < 8; ++i) {
    short8 b = (short8){0, 0, 0, 0, 0, 0, 0, 0};
    if (q < 2) {
      float4 P = pts[qbase + i * 16 + n];
      unsigned short xh = f2bf(P.x), yh = f2bf(P.y), zh = f2bf(P.z);
      unsigned short xl = f2bf(P.x - bf2f(xh));
      unsigned short yl = f2bf(P.y - bf2f(yh));
      unsigned short zl = f2bf(P.z - bf2f(zh));
      if (q == 0)
        b = (short8){(short)xh, (short)xh, (short)xl, (short)yh,
                     (short)yh, (short)yl, (short)zh, (short)zh};
      else
        b = (short8){(short)zl, one_bf, one_bf, one_bf, 0, 0, 0, 0};
    }
    bfr[i] = b;
    mn[i] = 3.0e38f;
  }

  floatx4 zc = {0.0f, 0.0f, 0.0f, 0.0f};
  // A address: quads 0/1 read their 16B K-slice; quads 2/3 read the shared
  // zero block (same-address broadcast, conflict-free).
  const unsigned short* aptr = sc + (q < 2 ? (q * 128 + n * 8) : CCH * 16);

  for (int ctile = 0; ctile < CCH / 16; ++ctile) {
    short8 a = *(const short8*)(aptr + ctile * 256);
#pragma unroll
    for (int i = 0; i < 8; ++i) {
      floatx4 dr = mfma_bf16_v(a, bfr[i], zc);
      // D col = lane&15 = query n (R7-verified end-to-end)
      mn[i] = fminf(fminf(fminf(dr[0], dr[1]), fminf(dr[2], dr[3])), mn[i]);
    }
  }

#pragma unroll
  for (int i = 0; i < 8; ++i) {
    float m = mn[i];
    m = fminf(m, __shfl_xor(m, 16));
    m = fminf(m, __shfl_xor(m, 32));
    if (lane < 16) {
      unsigned bb = __float_as_uint(m);
      unsigned e = (bb & 0x80000000u) ? ~bb : (bb | 0x80000000u);
      atomicMin(&minarr[qbase + i * 16 + lane], e);
    }
  }

  // ---- last block of this dir does the per-dir reduction ----
  __threadfence();
  __syncthreads();
  if (t == 0) s_ticket = atomicAdd(&dcnt[d], 1u);
  __syncthreads();
  if (s_ticket != 127u) return;
  __threadfence();

  float wsum = 0.0f, msum = 0.0f;
#pragma unroll 4
  for (int j = 0; j < 32; ++j) {
    int k = j * 256 + t;
    unsigned u = __hip_atomic_load(&minarr[(size_t)d * kNP + k],
                                   __ATOMIC_RELAXED, __HIP_MEMORY_SCOPE_AGENT);
    unsigned bb = (u & 0x80000000u) ? (u ^ 0x80000000u) : ~u;
    float mnv = __uint_as_float(bb);
    float4 P = pts[(size_t)d * kNP + k];
    if (P.w < 16384.0f) {
      wsum += P.w + mnv;
      msum += 1.0f;
    }
  }
#pragma unroll
  for (int off = 32; off; off >>= 1) {
    wsum += __shfl_down(wsum, off);
    msum += __shfl_down(msum, off);
  }
  if ((t & 63) == 0) { sw[t >> 6] = wsum; sm[t >> 6] = msum; }
  __syncthreads();
  if (t == 0) {
    float ws_ = sw[0] + sw[1] + sw[2] + sw[3];
    float ms_ = sm[0] + sm[1] + sm[2] + sm[3];
    mval[d] = ws_ / fmaxf(ms_, 1.0f);
    __threadfence();
    s_ticket = atomicAdd(acnt, 1u);
  }
  __syncthreads();
  if (s_ticket != (unsigned)(kDirs - 1)) return;
  // ---- very last block combines 16 dir values into the 12 outputs ----
  if (t == 0) {
    __threadfence();
    float mv[kDirs];
    for (int dd = 0; dd < kDirs; ++dd)
      mv[dd] = __hip_atomic_load(&mval[dd], __ATOMIC_RELAXED,
                                 __HIP_MEMORY_SCOPE_AGENT);
    for (int s = 0; s < kS; ++s) {
      float acc = 0.0f;
      for (int b = 0; b < kB; ++b) {
        int p = b * kS + s;
        float tens = mv[2 * p] + mv[2 * p + 1];
        out[kS + s * kB + b] = tens;
        acc += tens;
      }
      out[s] = acc * (1.0f / kB);
    }
  }
}

extern "C" void kernel_launch(void* const* d_in, const int* in_sizes, int n_in,
                              void* d_out, int out_size, void* d_ws, size_t ws_size,
                              hipStream_t stream) {
  const float* rv = (const float*)d_in[0];
  const float* tgt = (const float*)d_in[1];
  float* ws = (float*)d_ws;
  unsigned short* cf = (unsigned short*)ws;
  float4* pts = (float4*)(ws + OFF_PTS);
  unsigned* minarr = (unsigned*)(ws + OFF_MIN);
  float* mval = ws + OFF_MVAL;
  unsigned* dcnt = (unsigned*)(ws + OFF_DCNT);
  unsigned* acnt = (unsigned*)(ws + OFF_ACNT);
  float* out = (float*)d_out;

  hipLaunchKernelGGL(prep_kernel, dim3(kPairs * kNP / 256), dim3(256), 0, stream,
                     rv, tgt, cf, pts, minarr, mval, dcnt, acnt);
  hipLaunchKernelGGL(nn_kernel, dim3(kDirs * NQB * NCC), dim3(256), 0, stream,
                     cf, pts, minarr, mval, dcnt, acnt, out);
}

// Round 11
// 216.154 us; speedup vs baseline: 1.1765x; 1.1765x over previous
//
#include <hip/hip_runtime.h>
#include <math.h>

constexpr int kH = 64, kW = 128, kB = 2, kS = 4;
constexpr int kNP = kH * kW;          // 8192 points per set
constexpr int kPairs = kB * kS;       // 8
constexpr int kDirs = kPairs * 2;     // 16
constexpr float kPen = 32768.0f;      // exclusion penalty (bf16-exact pow2)
constexpr float kPi = 3.14159265358979323846f;
constexpr float kFovUp = 3.0f * kPi / 180.0f;
constexpr float kFovDown = -25.0f * kPi / 180.0f;

typedef short short8 __attribute__((ext_vector_type(8)));
typedef unsigned short ushort8 __attribute__((ext_vector_type(8)));
typedef float floatx4 __attribute__((ext_vector_type(4)));

// nn tiling (mfma_f32_16x16x32_bf16 intrinsic + fminf folds: the R7 anchor):
// block = 256 (4 waves); per wave 8 query tiles of 16 = 128 queries
// -> 512 queries/block. Candidate chunk = 1024 built in LDS (32 KB).
constexpr int NCC = 8;                // candidate chunks
constexpr int CCH = kNP / NCC;        // 1024 candidates
constexpr int NQB = 16;               // query blocks (8192/512)
// grid = 16 dirs * 16 * 8 = 2048 blocks, 128 blocks per dir

// ws layout (float offsets) — cf eliminated (records built in LDS from pts)
// pts  : [kDirs][kNP] float4 -> 524288 floats @ 0   (2 MB)
// min  : [kDirs][kNP] u32    -> 131072 @ 524288     (0.5 MB)
// mval : [kDirs] f32         -> 16 @ 655360
// dcnt : [kDirs] u32         -> 16 @ 655376
// acnt : u32                 -> 1  @ 655392
constexpr size_t OFF_MIN = 524288;
constexpr size_t OFF_MVAL = 655360;
constexpr size_t OFF_DCNT = 655376;
constexpr size_t OFF_ACNT = 655392;

__device__ __forceinline__ unsigned short f2bf(float v) {
  unsigned u = __float_as_uint(v);
  unsigned r = u + 0x7FFFu + ((u >> 16) & 1u);   // RNE
  return (unsigned short)(r >> 16);
}
__device__ __forceinline__ float bf2f(unsigned short b) {
  return __uint_as_float(((unsigned)b) << 16);
}

// Candidate record F (16 bf16 slots; K-quads: q0=k0..7, q1=k8..15, q2/q3=0)
// pairs with query record G:
//  k : 0    1    2    3    4    5    6    7  | 8    9    10   11   12-15
//  F : Xh   Xl   Xh   Yh   Yl   Yh   Zh   Zl | Zh   Ch   Cl   Cl2  0
//  G : xh   xh   xl   yh   yh   yl   zh   zh | zl   1    1    1    0
// sum_k F*G = X*x + Y*y + Z*z + ct  (drops only lo*lo terms ~2e-4)

__global__ __launch_bounds__(256) void prep_kernel(
    const float* __restrict__ rv, const float* __restrict__ tgt,
    float4* __restrict__ pts, unsigned* __restrict__ minarr,
    float* __restrict__ mval, unsigned* __restrict__ dcnt,
    unsigned* __restrict__ acnt) {
  int idx = blockIdx.x * 256 + threadIdx.x;   // [0, kPairs*kNP)
  int p = idx >> 13;
  int k = idx & (kNP - 1);
  int h = k >> 7;
  int w = k & 127;

  float r = rv[idx];
  float pitch = (1.0f - (h + 0.5f) * (1.0f / kH)) * (kFovUp - kFovDown) + kFovDown;
  float yaw = -(((w + 0.5f) * (1.0f / kW)) * 2.0f - 1.0f) * kPi;
  float cp = __cosf(pitch), sp = __sinf(pitch);
  float cy = __cosf(yaw), sy = __sinf(yaw);
  float px = r * cp * cy, py = r * cp * sy, pz = r * sp;
  float mo = (r > 0.0f) ? 1.0f : 0.0f;

  const float* tb = tgt + (size_t)p * 4 * kNP;
  float mt = (tb[k] > 0.0f) ? 1.0f : 0.0f;
  float tx = tb[kNP + k], ty = tb[2 * kNP + k], tz = tb[3 * kNP + k];

  float no = px * px + py * py + pz * pz;
  float nt = tx * tx + ty * ty + tz * tz;
  float co = no + kPen * (1.0f - mo);
  float ct = nt + kPen * (1.0f - mt);

  int d0 = 2 * p, d1 = d0 + 1;
  // pts.w < 16384 <=> valid point; equals |p|^2 then. Also: candidates of
  // dir d are exactly pts[d^1] (dir0 candidates = tgt pts = dir1 queries).
  pts[(size_t)d0 * kNP + k] = make_float4(px, py, pz, co);
  pts[(size_t)d1 * kNP + k] = make_float4(tx, ty, tz, ct);

  minarr[(size_t)d0 * kNP + k] = 0xFFFFFFFFu;
  minarr[(size_t)d1 * kNP + k] = 0xFFFFFFFFu;
  if (idx < kDirs) { dcnt[idx] = 0u; mval[idx] = 0.0f; }
  if (idx == kDirs) *acnt = 0u;
}

__global__ __launch_bounds__(256, 4) void nn_kernel(
    const float4* __restrict__ pts, unsigned* __restrict__ minarr,
    float* __restrict__ mval, unsigned* __restrict__ dcnt,
    unsigned* __restrict__ acnt, float* __restrict__ out) {
  // 32 KB candidate records (64 tiles of [16 x lo8][16 x hi8]) + 32 B zero tile
  __shared__ __align__(16) unsigned short sc[CCH * 16 + 16];
  __shared__ unsigned s_ticket;
  __shared__ float sw[4], sm[4];

  int bid = blockIdx.x;
  int d = bid >> 7;            // 128 blocks per dir
  int qb = (bid >> 3) & 15;
  int ch = bid & 7;
  int t = threadIdx.x;

  // ---- build candidate records in LDS directly from pts[d^1] ----
  const float4* cand = pts + (size_t)(d ^ 1) * kNP + ch * CCH;
#pragma unroll
  for (int i = 0; i < 4; ++i) {
    int j = t + i * 256;
    float4 P = cand[j];
    float X = -2.0f * P.x, Y = -2.0f * P.y, Z = -2.0f * P.z;
    float ct = P.w;
    unsigned short Xh = f2bf(X), Yh = f2bf(Y), Zh = f2bf(Z);
    unsigned short Xl = f2bf(X - bf2f(Xh));
    unsigned short Yl = f2bf(Y - bf2f(Yh));
    unsigned short Zl = f2bf(Z - bf2f(Zh));
    unsigned short Ch = f2bf(ct);
    float c1 = ct - bf2f(Ch);
    unsigned short Cl = f2bf(c1);
    unsigned short Cl2 = f2bf(c1 - bf2f(Cl));
    unsigned short* dst = sc + (j >> 4) * 256 + (j & 15) * 8;
    *(ushort8*)dst = (ushort8){Xh, Xl, Xh, Yh, Yl, Yh, Zh, Zl};
    *(ushort8*)(dst + 128) = (ushort8){Zh, Ch, Cl, Cl2, 0, 0, 0, 0};
  }
  if (t < 2) ((float4*)(sc + CCH * 16))[t] = make_float4(0.f, 0.f, 0.f, 0.f);
  __syncthreads();

  int wave = t >> 6, lane = t & 63;
  int n = lane & 15, q = lane >> 4;    // q = K-quad (HW-verified layout)
  int qbase = d * kNP + qb * 512 + wave * 128;

  const short one_bf = (short)0x3F80;  // bf16(1.0)
  short8 bfr[8];
  float mn[8];
#pragma unroll
  for (int i = 0; i < 8; ++i) {
    short8 b = (short8){0, 0, 0, 0, 0, 0, 0, 0};
    if (q < 2) {
      float4 P = pts[qbase + i * 16 + n];
      unsigned short xh = f2bf(P.x), yh = f2bf(P.y), zh = f2bf(P.z);
      unsigned short xl = f2bf(P.x - bf2f(xh));
      unsigned short yl = f2bf(P.y - bf2f(yh));
      unsigned short zl = f2bf(P.z - bf2f(zh));
      if (q == 0)
        b = (short8){(short)xh, (short)xh, (short)xl, (short)yh,
                     (short)yh, (short)yl, (short)zh, (short)zh};
      else
        b = (short8){(short)zl, one_bf, one_bf, one_bf, 0, 0, 0, 0};
    }
    bfr[i] = b;
    mn[i] = 3.0e38f;
  }

  floatx4 zc = {0.0f, 0.0f, 0.0f, 0.0f};
  // A addressing: quads 0/1 walk their K-slice (stride 512 B); quads 2/3 sit
  // on the shared zero tile (same-address broadcast). No cndmask in the loop.
  const unsigned short* aptr = (q < 2) ? (sc + q * 128 + n * 8) : (sc + CCH * 16);
  int astep = (q < 2) ? 256 : 0;

#pragma unroll 2
  for (int ctile = 0; ctile < CCH / 16; ++ctile) {
    short8 a = *(const short8*)aptr;
    aptr += astep;
#pragma unroll
    for (int i = 0; i < 8; ++i) {
      floatx4 dr = __builtin_amdgcn_mfma_f32_16x16x32_bf16(a, bfr[i], zc, 0, 0, 0);
      // min3-shaped fold (2 x v_min3, compiler-emitted => hazard-safe)
      float u = fminf(fminf(dr[0], dr[1]), dr[2]);
      mn[i] = fminf(fminf(u, dr[3]), mn[i]);
    }
  }

#pragma unroll
  for (int i = 0; i < 8; ++i) {
    float m = mn[i];
    m = fminf(m, __shfl_xor(m, 16));
    m = fminf(m, __shfl_xor(m, 32));
    if (lane < 16) {
      unsigned bb = __float_as_uint(m);
      unsigned e = (bb & 0x80000000u) ? ~bb : (bb | 0x80000000u);
      atomicMin(&minarr[qbase + i * 16 + lane], e);
    }
  }

  // ---- last block of this dir does the per-dir reduction ----
  __threadfence();
  __syncthreads();
  if (t == 0) s_ticket = atomicAdd(&dcnt[d], 1u);
  __syncthreads();
  if (s_ticket != 127u) return;
  __threadfence();

  float wsum = 0.0f, msum = 0.0f;
#pragma unroll 4
  for (int j = 0; j < 32; ++j) {
    int k = j * 256 + t;
    unsigned u = __hip_atomic_load(&minarr[(size_t)d * kNP + k],
                                   __ATOMIC_RELAXED, __HIP_MEMORY_SCOPE_AGENT);
    unsigned bb = (u & 0x80000000u) ? (u ^ 0x80000000u) : ~u;
    float mnv = __uint_as_float(bb);
    float4 P = pts[(size_t)d * kNP + k];
    if (P.w < 16384.0f) {
      wsum += P.w + mnv;
      msum += 1.0f;
    }
  }
#pragma unroll
  for (int off = 32; off; off >>= 1) {
    wsum += __shfl_down(wsum, off);
    msum += __shfl_down(msum, off);
  }
  if ((t & 63) == 0) { sw[t >> 6] = wsum; sm[t >> 6] = msum; }
  __syncthreads();
  if (t == 0) {
    float ws_ = sw[0] + sw[1] + sw[2] + sw[3];
    float ms_ = sm[0] + sm[1] + sm[2] + sm[3];
    mval[d] = ws_ / fmaxf(ms_, 1.0f);
    __threadfence();
    s_ticket = atomicAdd(acnt, 1u);
  }
  __syncthreads();
  if (s_ticket != (unsigned)(kDirs - 1)) return;
  // ---- very last block combines 16 dir values into the 12 outputs ----
  if (t == 0) {
    __threadfence();
    float mv[kDirs];
    for (int dd = 0; dd < kDirs; ++dd)
      mv[dd] = __hip_atomic_load(&mval[dd], __ATOMIC_RELAXED,
                                 __HIP_MEMORY_SCOPE_AGENT);
    for (int s = 0; s < kS; ++s) {
      float acc = 0.0f;
      for (int b = 0; b < kB; ++b) {
        int p = b * kS + s;
        float tens = mv[2 * p] + mv[2 * p + 1];
        out[kS + s * kB + b] = tens;
        acc += tens;
      }
      out[s] = acc * (1.0f / kB);
    }
  }
}

extern "C" void kernel_launch(void* const* d_in, const int* in_sizes, int n_in,
                              void* d_out, int out_size, void* d_ws, size_t ws_size,
                              hipStream_t stream) {
  const float* rv = (const float*)d_in[0];
  const float* tgt = (const float*)d_in[1];
  float* ws = (float*)d_ws;
  float4* pts = (float4*)ws;
  unsigned* minarr = (unsigned*)(ws + OFF_MIN);
  float* mval = ws + OFF_MVAL;
  unsigned* dcnt = (unsigned*)(ws + OFF_DCNT);
  unsigned* acnt = (unsigned*)(ws + OFF_ACNT);
  float* out = (float*)d_out;

  hipLaunchKernelGGL(prep_kernel, dim3(kPairs * kNP / 256), dim3(256), 0, stream,
                     rv, tgt, pts, minarr, mval, dcnt, acnt);
  hipLaunchKernelGGL(nn_kernel, dim3(kDirs * NQB * NCC), dim3(256), 0, stream,
                     pts, minarr, mval, dcnt, acnt, out);
}

// Round 12
// 119.021 us; speedup vs baseline: 2.1367x; 1.8161x over previous
//
#include <hip/hip_runtime.h>
#include <math.h>

constexpr int kH = 64, kW = 128, kB = 2, kS = 4;
constexpr int kNP = kH * kW;          // 8192 points per set
constexpr int kPairs = kB * kS;       // 8
constexpr int kDirs = kPairs * 2;     // 16
constexpr float kPen = 32768.0f;      // exclusion penalty (bf16-exact pow2)
constexpr float kPi = 3.14159265358979323846f;
constexpr float kFovUp = 3.0f * kPi / 180.0f;
constexpr float kFovDown = -25.0f * kPi / 180.0f;

typedef short short8 __attribute__((ext_vector_type(8)));
typedef unsigned short ushort8 __attribute__((ext_vector_type(8)));
typedef float floatx4 __attribute__((ext_vector_type(4)));

// nn tiling (mfma_f32_16x16x32_bf16 intrinsic + fminf folds: the R7 anchor):
// block = 256 (4 waves); per wave 8 query tiles of 16 = 128 queries
// -> 512 queries/block. Candidate chunk = 1024 built in LDS (32 KB).
constexpr int NCC = 8;                // candidate chunks
constexpr int CCH = kNP / NCC;        // 1024 candidates
constexpr int NQB = 16;               // query blocks (8192/512)
// grid = 16 dirs * 16 * 8 = 2048 blocks, 128 blocks per dir

// ws layout (float offsets) — cf eliminated (records built in LDS from pts)
// pts  : [kDirs][kNP] float4 -> 524288 floats @ 0   (2 MB)
// min  : [kDirs][kNP] u32    -> 131072 @ 524288     (0.5 MB)
// mval : [kDirs] f32         -> 16 @ 655360
// dcnt : [kDirs] u32         -> 16 @ 655376
// acnt : u32                 -> 1  @ 655392
constexpr size_t OFF_MIN = 524288;
constexpr size_t OFF_MVAL = 655360;
constexpr size_t OFF_DCNT = 655376;
constexpr size_t OFF_ACNT = 655392;

__device__ __forceinline__ unsigned short f2bf(float v) {
  unsigned u = __float_as_uint(v);
  unsigned r = u + 0x7FFFu + ((u >> 16) & 1u);   // RNE
  return (unsigned short)(r >> 16);
}
__device__ __forceinline__ float bf2f(unsigned short b) {
  return __uint_as_float(((unsigned)b) << 16);
}

// Candidate record F (16 bf16 slots; K-quads: q0=k0..7, q1=k8..15, q2/q3=0)
// pairs with query record G:
//  k : 0    1    2    3    4    5    6    7  | 8    9    10   11   12-15
//  F : Xh   Xl   Xh   Yh   Yl   Yh   Zh   Zl | Zh   Ch   Cl   Cl2  0
//  G : xh   xh   xl   yh   yh   yl   zh   zh | zl   1    1    1    0
// sum_k F*G = X*x + Y*y + Z*z + ct  (drops only lo*lo terms ~2e-4)

__global__ __launch_bounds__(256) void prep_kernel(
    const float* __restrict__ rv, const float* __restrict__ tgt,
    float4* __restrict__ pts, unsigned* __restrict__ minarr,
    float* __restrict__ mval, unsigned* __restrict__ dcnt,
    unsigned* __restrict__ acnt) {
  int idx = blockIdx.x * 256 + threadIdx.x;   // [0, kPairs*kNP)
  int p = idx >> 13;
  int k = idx & (kNP - 1);
  int h = k >> 7;
  int w = k & 127;

  float r = rv[idx];
  float pitch = (1.0f - (h + 0.5f) * (1.0f / kH)) * (kFovUp - kFovDown) + kFovDown;
  float yaw = -(((w + 0.5f) * (1.0f / kW)) * 2.0f - 1.0f) * kPi;
  float cp = __cosf(pitch), sp = __sinf(pitch);
  float cy = __cosf(yaw), sy = __sinf(yaw);
  float px = r * cp * cy, py = r * cp * sy, pz = r * sp;
  float mo = (r > 0.0f) ? 1.0f : 0.0f;

  const float* tb = tgt + (size_t)p * 4 * kNP;
  float mt = (tb[k] > 0.0f) ? 1.0f : 0.0f;
  float tx = tb[kNP + k], ty = tb[2 * kNP + k], tz = tb[3 * kNP + k];

  float no = px * px + py * py + pz * pz;
  float nt = tx * tx + ty * ty + tz * tz;
  float co = no + kPen * (1.0f - mo);
  float ct = nt + kPen * (1.0f - mt);

  int d0 = 2 * p, d1 = d0 + 1;
  // pts.w < 16384 <=> valid point; equals |p|^2 then. Also: candidates of
  // dir d are exactly pts[d^1] (dir0 candidates = tgt pts = dir1 queries).
  pts[(size_t)d0 * kNP + k] = make_float4(px, py, pz, co);
  pts[(size_t)d1 * kNP + k] = make_float4(tx, ty, tz, ct);

  minarr[(size_t)d0 * kNP + k] = 0xFFFFFFFFu;
  minarr[(size_t)d1 * kNP + k] = 0xFFFFFFFFu;
  if (idx < kDirs) { dcnt[idx] = 0u; mval[idx] = 0.0f; }
  if (idx == kDirs) *acnt = 0u;
}

__global__ __launch_bounds__(256, 4) void nn_kernel(
    const float4* __restrict__ pts, unsigned* __restrict__ minarr,
    float* __restrict__ mval, unsigned* __restrict__ dcnt,
    unsigned* __restrict__ acnt, float* __restrict__ out) {
  // 32 KB candidate records (64 tiles of [16 x lo8][16 x hi8]) + 32 B zero tile
  __shared__ __align__(16) unsigned short sc[CCH * 16 + 16];
  __shared__ unsigned s_ticket;
  __shared__ float sw[4], sm[4];

  int bid = blockIdx.x;
  int d = bid >> 7;            // 128 blocks per dir
  int qb = (bid >> 3) & 15;
  int ch = bid & 7;
  int t = threadIdx.x;

  // ---- build candidate records in LDS directly from pts[d^1] ----
  const float4* cand = pts + (size_t)(d ^ 1) * kNP + ch * CCH;
#pragma unroll
  for (int i = 0; i < 4; ++i) {
    int j = t + i * 256;
    float4 P = cand[j];
    float X = -2.0f * P.x, Y = -2.0f * P.y, Z = -2.0f * P.z;
    float ct = P.w;
    unsigned short Xh = f2bf(X), Yh = f2bf(Y), Zh = f2bf(Z);
    unsigned short Xl = f2bf(X - bf2f(Xh));
    unsigned short Yl = f2bf(Y - bf2f(Yh));
    unsigned short Zl = f2bf(Z - bf2f(Zh));
    unsigned short Ch = f2bf(ct);
    float c1 = ct - bf2f(Ch);
    unsigned short Cl = f2bf(c1);
    unsigned short Cl2 = f2bf(c1 - bf2f(Cl));
    unsigned short* dst = sc + (j >> 4) * 256 + (j & 15) * 8;
    *(ushort8*)dst = (ushort8){Xh, Xl, Xh, Yh, Yl, Yh, Zh, Zl};
    *(ushort8*)(dst + 128) = (ushort8){Zh, Ch, Cl, Cl2, 0, 0, 0, 0};
  }
  if (t < 2) ((float4*)(sc + CCH * 16))[t] = make_float4(0.f, 0.f, 0.f, 0.f);
  __syncthreads();

  int wave = t >> 6, lane = t & 63;
  int n = lane & 15, q = lane >> 4;    // q = K-quad (HW-verified layout)
  int qbase = d * kNP + qb * 512 + wave * 128;

  const short one_bf = (short)0x3F80;  // bf16(1.0)
  short8 bfr[8];
  float mn[8];
#pragma unroll
  for (int i = 0; i < 8; ++i) {
    short8 b = (short8){0, 0, 0, 0, 0, 0, 0, 0};
    if (q < 2) {
      float4 P = pts[qbase + i * 16 + n];
      unsigned short xh = f2bf(P.x), yh = f2bf(P.y), zh = f2bf(P.z);
      unsigned short xl = f2bf(P.x - bf2f(xh));
      unsigned short yl = f2bf(P.y - bf2f(yh));
      unsigned short zl = f2bf(P.z - bf2f(zh));
      if (q == 0)
        b = (short8){(short)xh, (short)xh, (short)xl, (short)yh,
                     (short)yh, (short)yl, (short)zh, (short)zh};
      else
        b = (short8){(short)zl, one_bf, one_bf, one_bf, 0, 0, 0, 0};
    }
    bfr[i] = b;
    mn[i] = 3.0e38f;
  }

  floatx4 zc = {0.0f, 0.0f, 0.0f, 0.0f};
  // A addressing: quads 0/1 walk their K-slice (stride 512 B); quads 2/3 sit
  // on the shared zero tile (same-address broadcast). No cndmask in the loop.
  const unsigned short* aptr = (q < 2) ? (sc + q * 128 + n * 8) : (sc + CCH * 16);
  int astep = (q < 2) ? 256 : 0;

#pragma unroll 2
  for (int ctile = 0; ctile < CCH / 16; ++ctile) {
    short8 a = *(const short8*)aptr;
    aptr += astep;
#pragma unroll
    for (int i = 0; i < 8; ++i) {
      floatx4 dr = __builtin_amdgcn_mfma_f32_16x16x32_bf16(a, bfr[i], zc, 0, 0, 0);
      // min3-shaped fold (2 x v_min3, compiler-emitted => hazard-safe)
      float u = fminf(fminf(dr[0], dr[1]), dr[2]);
      mn[i] = fminf(fminf(u, dr[3]), mn[i]);
    }
  }

#pragma unroll
  for (int i = 0; i < 8; ++i) {
    float m = mn[i];
    m = fminf(m, __shfl_xor(m, 16));
    m = fminf(m, __shfl_xor(m, 32));
    if (lane < 16) {
      unsigned bb = __float_as_uint(m);
      unsigned e = (bb & 0x80000000u) ? ~bb : (bb | 0x80000000u);
      atomicMin(&minarr[qbase + i * 16 + lane], e);
    }
  }

  // ---- last block of this dir does the per-dir reduction ----
  // NO __threadfence here. R8/R10/R11 post-mortem: per-block device fences
  // emit buffer_wbl2/buffer_inv L2-maintenance ops that serialized
  // device-wide (~2x kernel stall). Not needed: all cross-block data
  // (minarr/dcnt/mval/acnt) moves through device-scope atomics at the
  // coherent point, and __syncthreads' implicit s_waitcnt vmcnt(0) drains
  // our atomicMins before the ticket increment below.
  __syncthreads();
  if (t == 0)
    s_ticket = __hip_atomic_fetch_add(&dcnt[d], 1u, __ATOMIC_RELAXED,
                                      __HIP_MEMORY_SCOPE_AGENT);
  __syncthreads();
  if (s_ticket != 127u) return;

  float wsum = 0.0f, msum = 0.0f;
#pragma unroll 4
  for (int j = 0; j < 32; ++j) {
    int k = j * 256 + t;
    unsigned u = __hip_atomic_load(&minarr[(size_t)d * kNP + k],
                                   __ATOMIC_RELAXED, __HIP_MEMORY_SCOPE_AGENT);
    unsigned bb = (u & 0x80000000u) ? (u ^ 0x80000000u) : ~u;
    float mnv = __uint_as_float(bb);
    float4 P = pts[(size_t)d * kNP + k];
    if (P.w < 16384.0f) {
      wsum += P.w + mnv;
      msum += 1.0f;
    }
  }
#pragma unroll
  for (int off = 32; off; off >>= 1) {
    wsum += __shfl_down(wsum, off);
    msum += __shfl_down(msum, off);
  }
  if ((t & 63) == 0) { sw[t >> 6] = wsum; sm[t >> 6] = msum; }
  __syncthreads();
  if (t == 0) {
    float ws_ = sw[0] + sw[1] + sw[2] + sw[3];
    float ms_ = sm[0] + sm[1] + sm[2] + sm[3];
    __hip_atomic_store(&mval[d], ws_ / fmaxf(ms_, 1.0f), __ATOMIC_RELAXED,
                       __HIP_MEMORY_SCOPE_AGENT);
    // ACQ_REL: release publishes our mval store (waitcnt, no L2 flush
    // needed for an agent-scope atomic store), acquire lets the final
    // winner read the other 15 mvals. Only 16 of these per launch.
    s_ticket = __hip_atomic_fetch_add(acnt, 1u, __ATOMIC_ACQ_REL,
                                      __HIP_MEMORY_SCOPE_AGENT);
  }
  __syncthreads();
  if (s_ticket != (unsigned)(kDirs - 1)) return;
  // ---- very last block combines 16 dir values into the 12 outputs ----
  if (t == 0) {
    float mv[kDirs];
    for (int dd = 0; dd < kDirs; ++dd)
      mv[dd] = __hip_atomic_load(&mval[dd], __ATOMIC_RELAXED,
                                 __HIP_MEMORY_SCOPE_AGENT);
    for (int s = 0; s < kS; ++s) {
      float acc = 0.0f;
      for (int b = 0; b < kB; ++b) {
        int p = b * kS + s;
        float tens = mv[2 * p] + mv[2 * p + 1];
        out[kS + s * kB + b] = tens;
        acc += tens;
      }
      out[s] = acc * (1.0f / kB);
    }
  }
}

extern "C" void kernel_launch(void* const* d_in, const int* in_sizes, int n_in,
                              void* d_out, int out_size, void* d_ws, size_t ws_size,
                              hipStream_t stream) {
  const float* rv = (const float*)d_in[0];
  const float* tgt = (const float*)d_in[1];
  float* ws = (float*)d_ws;
  float4* pts = (float4*)ws;
  unsigned* minarr = (unsigned*)(ws + OFF_MIN);
  float* mval = ws + OFF_MVAL;
  unsigned* dcnt = (unsigned*)(ws + OFF_DCNT);
  unsigned* acnt = (unsigned*)(ws + OFF_ACNT);
  float* out = (float*)d_out;

  hipLaunchKernelGGL(prep_kernel, dim3(kPairs * kNP / 256), dim3(256), 0, stream,
                     rv, tgt, pts, minarr, mval, dcnt, acnt);
  hipLaunchKernelGGL(nn_kernel, dim3(kDirs * NQB * NCC), dim3(256), 0, stream,
                     pts, minarr, mval, dcnt, acnt, out);
}